// Round 13
// baseline (116.053 us; speedup 1.0000x reference)
//
#include <hip/hip_runtime.h>

#define HEADS 4
#define CDIM  64
#define INDIM 128
#define NEG   0.2f
#define CAP     128   // LDS edge slots per wave (aggr)
#define FASTCAP 120   // fast-path edge limit (pad room to CAP, mult-of-8)
#define NPB     256   // partition blocks for bucket sort

typedef __attribute__((ext_vector_type(8))) short short8;
typedef __attribute__((ext_vector_type(4))) float f32x4;
typedef _Float16 half2_t __attribute__((ext_vector_type(2)));

__device__ __forceinline__ float wave_sum(float v) {
#pragma unroll
    for (int o = 32; o > 0; o >>= 1) v += __shfl_xor(v, o, 64);
    return v;
}
__device__ __forceinline__ int wave_sum_i(int v) {
#pragma unroll
    for (int o = 32; o > 0; o >>= 1) v += __shfl_xor(v, o, 64);
    return v;
}

// f32 -> bf16 bits (RNE) — for the MFMA operand prep only
__device__ __forceinline__ unsigned short f2bf(float f) {
    unsigned u = __float_as_uint(f);
    u = (u + 0x7FFFu + ((u >> 16) & 1u)) >> 16;
    return (unsigned short)u;
}

__device__ __forceinline__ unsigned pk_f16(float a, float b) {
    auto h = __builtin_amdgcn_cvt_pkrtz(a, b);   // __fp16 x2
    return __builtin_bit_cast(unsigned, h);
}
__device__ __forceinline__ half2_t as_h2(unsigned u) {
    return __builtin_bit_cast(half2_t, u);
}

__device__ __forceinline__ float lrelu(float a) { return a >= 0.f ? a : NEG * a; }

// raw-e accumulate: 4 heads, f32 accum from f16 operands (v_fma_mix)
__device__ __forceinline__ void acc_edge(uint4 c, uint2 h,
    float& a0, float& a1, float& a2, float& a3)
{
    half2_t e01 = as_h2(c.x), e23 = as_h2(c.y);
    half2_t h01 = as_h2(h.x), h23 = as_h2(h.y);
    a0 = fmaf((float)e01.x, (float)h01.x, a0);
    a1 = fmaf((float)e01.y, (float)h01.y, a1);
    a2 = fmaf((float)e23.x, (float)h23.x, a2);
    a3 = fmaf((float)e23.y, (float)h23.y, a3);
}

// ---------------- count (bucket hist) + Waug prep, merged ----------------
__global__ __launch_bounds__(256) void k_count_prep(const int* __restrict__ ei,
    int E, int EPB, int NBUK, int* __restrict__ counts,
    const float* __restrict__ W, const float* __restrict__ att_src,
    const float* __restrict__ att_dst, unsigned short* __restrict__ Waug)
{
    __shared__ int hist[256];
    const int t = threadIdx.x, blk = blockIdx.x;
    hist[t] = 0;
    __syncthreads();
    const int e0 = blk * EPB;
    for (int j = t; j < EPB; j += 256) {
        int e = e0 + j;
        if (e < E) atomicAdd(&hist[ei[E + e] >> 8], 1);   // LDS atomic
    }
    __syncthreads();
    if (t < NBUK) counts[t * NPB + blk] = hist[t];

    // Waug prep: one (col,k) entry per global thread
    int idx = blk * 256 + t;
    if (idx < 272 * 128) {
        int c = idx >> 7, k = idx & 127;
        float val;
        if (c < 256) {
            val = W[k * 256 + c];
        } else if (c < 260) {
            int q = c - 256; float s = 0.f;
            for (int j = 0; j < 64; ++j) s += W[k * 256 + q * 64 + j] * att_src[q * 64 + j];
            val = s;
        } else if (c < 264) {
            int q = c - 260; float s = 0.f;
            for (int j = 0; j < 64; ++j) s += W[k * 256 + q * 64 + j] * att_dst[q * 64 + j];
            val = s;
        } else {
            val = 0.f;
        }
        Waug[c * 128 + k] = f2bf(val);
    }
}

// ---------------- scan, phase 1: per-block sums ----------------
__global__ __launch_bounds__(256) void k_scan1(const int* __restrict__ arr,
    int* __restrict__ bsum, int n)
{
    const int t = threadIdx.x, lane = t & 63, wv = t >> 6;
    int gid = blockIdx.x * 256 + t;
    int v = (gid < n) ? arr[gid] : 0;
    v = wave_sum_i(v);
    __shared__ int ws[4];
    if (lane == 0) ws[wv] = v;
    __syncthreads();
    if (t == 0) bsum[blockIdx.x] = ws[0] + ws[1] + ws[2] + ws[3];
}

// ---------------- scan, phase 2: finalize in place (self-computed prefix) ----------------
__global__ __launch_bounds__(256) void k_scanip2(int* __restrict__ arr,
    const int* __restrict__ bsum, int NB, int n)
{
    __shared__ int wred[4];
    __shared__ int wtot[4];
    __shared__ int spre;
    const int t = threadIdx.x, lane = t & 63, wv = t >> 6, b = blockIdx.x;

    int u0 = (t < NB && t < b) ? bsum[t] : 0;
    u0 = wave_sum_i(u0);
    if (lane == 0) wred[wv] = u0;
    __syncthreads();
    if (t == 0) spre = wred[0] + wred[1] + wred[2] + wred[3];
    __syncthreads();

    int gid = b * 256 + t;
    int v = (gid < n) ? arr[gid] : 0;
    int inc = v;
#pragma unroll
    for (int o = 1; o < 64; o <<= 1) {
        int u = __shfl_up(inc, o, 64);
        if (lane >= o) inc += u;
    }
    if (lane == 63) wtot[wv] = inc;
    __syncthreads();
    int wpre = 0;
    for (int w = 0; w < wv; ++w) wpre += wtot[w];
    int ex = inc - v + wpre + spre;
    if (gid < n) arr[gid] = ex;
}

// ---------------- partition: packed u32 (src<<8 | dst&255) ----------------
__global__ __launch_bounds__(256) void k_part(const int* __restrict__ ei,
    int E, int EPB, int NBUK, const int* __restrict__ counts,
    unsigned* __restrict__ srt)
{
    __shared__ int cb[256];
    const int t = threadIdx.x, blk = blockIdx.x;
    if (t < NBUK) cb[t] = counts[t * NPB + blk];
    __syncthreads();
    const int e0 = blk * EPB;
    for (int j = t; j < EPB; j += 256) {
        int e = e0 + j;
        if (e < E) {
            int s = ei[e], d = ei[E + e];
            int pos = atomicAdd(&cb[d >> 8], 1);   // LDS atomic
            srt[pos] = ((unsigned)s << 8) | ((unsigned)d & 255u);
        }
    }
}

// ---------------- per-bucket CSR ----------------
__global__ __launch_bounds__(256) void k_bcsr(const unsigned* __restrict__ srt,
    const int* __restrict__ counts, int E, int N, int NBUK,
    int* __restrict__ deg, int* __restrict__ off, int* __restrict__ csr)
{
    __shared__ int h[256];
    __shared__ int cur[256];
    __shared__ int wt[4];
    const int t = threadIdx.x, b = blockIdx.x;
    const int bb0 = counts[b * NPB];
    const int bb1 = (b + 1 < NBUK) ? counts[(b + 1) * NPB] : E;
    const int ne = bb1 - bb0;

    h[t] = 0;
    __syncthreads();
    for (int j = t; j < ne; j += 256) atomicAdd(&h[srt[bb0 + j] & 255u], 1);
    __syncthreads();

    int v = h[t];
    const int lane = t & 63, wv = t >> 6;
    int inc = v;
#pragma unroll
    for (int o = 1; o < 64; o <<= 1) {
        int u = __shfl_up(inc, o, 64);
        if (lane >= o) inc += u;
    }
    if (lane == 63) wt[wv] = inc;
    __syncthreads();
    int wpre = 0;
    for (int w = 0; w < wv; ++w) wpre += wt[w];
    int ex = inc - v + wpre;

    int node = (b << 8) + t;
    if (node < N) { deg[node] = v; off[node] = bb0 + ex; }
    cur[t] = bb0 + ex;
    __syncthreads();

    for (int j = t; j < ne; j += 256) {
        unsigned u = srt[bb0 + j];
        int pos = atomicAdd(&cur[u & 255u], 1);   // LDS atomic
        csr[pos] = (int)(u >> 8);
    }
}

// ---------------- MFMA projection: h (f16-packed) + logits ----------------
__global__ __launch_bounds__(512) void gemm_mfma(
    const float* __restrict__ x, const unsigned short* __restrict__ Waug,
    uint2* __restrict__ hp, float* __restrict__ a_src, float* __restrict__ a_dst,
    int N)
{
    extern __shared__ char smem[];
    const int t = threadIdx.x;

    const uint4* srcw = (const uint4*)Waug;
    for (int i = t; i < 272 * 16; i += 512) {
        int col = i >> 4, kc = i & 15;
        int off = col * 256 + ((kc * 16) ^ ((col & 7) << 4));
        *(uint4*)(smem + off) = srcw[i];
    }
    __syncthreads();

    const int lane = t & 63, wv = t >> 6;
    const int l = lane & 15, g = lane >> 4;
    const int rowbase = blockIdx.x * 128 + wv * 16;

    int anode = rowbase + l; if (anode >= N) anode = N - 1;
    const float4* xrow = (const float4*)(x + (size_t)anode * INDIM);

    short8 af[4];
#pragma unroll
    for (int ks = 0; ks < 4; ++ks) {
        float4 x0 = xrow[ks * 8 + g * 2];
        float4 x1 = xrow[ks * 8 + g * 2 + 1];
        short8 a;
        a[0] = (short)f2bf(x0.x); a[1] = (short)f2bf(x0.y);
        a[2] = (short)f2bf(x0.z); a[3] = (short)f2bf(x0.w);
        a[4] = (short)f2bf(x1.x); a[5] = (short)f2bf(x1.y);
        a[6] = (short)f2bf(x1.z); a[7] = (short)f2bf(x1.w);
        af[ks] = a;
    }

    f32x4 acc[17];
    const f32x4 zero = {0.f, 0.f, 0.f, 0.f};
#pragma unroll
    for (int tt = 0; tt < 17; ++tt) acc[tt] = zero;

    const int base_b = l * 256;
#pragma unroll
    for (int ks = 0; ks < 4; ++ks) {
        const int koff = (ks * 64 + g * 16) ^ ((l & 7) << 4);
#pragma unroll
        for (int tt = 0; tt < 17; ++tt) {
            short8 bf = *(const short8*)(smem + tt * 4096 + base_b + koff);
            acc[tt] = __builtin_amdgcn_mfma_f32_16x16x32_bf16(af[ks], bf, acc[tt], 0, 0, 0);
        }
    }

#pragma unroll
    for (int j = 0; j < 4; ++j) {
        int node = rowbase + g * 4 + j;
        if (node < N) {
#pragma unroll
            for (int u = 0; u < 4; ++u) {
                int ch = l + 16 * u;
                hp[(size_t)node * CDIM + ch] = make_uint2(
                    pk_f16(acc[u][j],     acc[4 + u][j]),
                    pk_f16(acc[8 + u][j], acc[12 + u][j]));
            }
            if (l < 4)      a_src[node * 4 + l]       = acc[16][j];
            else if (l < 8) a_dst[node * 4 + (l - 4)] = acc[16][j];
        }
    }
}

// ---------------- fused aggregation + LayerNorm + PReLU ----------------
// Post-normalized accumulate with an 8-deep software pipeline in Phase B:
// 8 slot-reads + 8 hp-gathers always in flight per wave.
__global__ __launch_bounds__(256) void aggr_fused(
    const int* __restrict__ off, const int* __restrict__ deg,
    const int* __restrict__ csr_src,
    const float4* __restrict__ a_src4, const float4* __restrict__ a_dst4,
    const uint2* __restrict__ hp,
    const float* __restrict__ bias, const float* __restrict__ gamma,
    const float* __restrict__ beta, const float* __restrict__ prelu,
    float* __restrict__ out, int N)
{
    __shared__ uint4 slot[4][CAP];
    const int wv   = threadIdx.x >> 6;
    const int lane = threadIdx.x & 63;
    const int wid  = (int)(blockIdx.x * 4u + wv);
    if (wid >= N) return;
    const int d = wid;
    uint4* sl = slot[wv];

    const float bl = bias[lane], gl = gamma[lane], bt = beta[lane], pw = prelu[0];
    const float4 ad  = a_dst4[d];
    const float4 asd = a_src4[d];
    const uint2  hd  = hp[(size_t)d * CDIM + lane];

    const int deg_d = deg[d];
    const int beg   = off[d];
    const int nv    = deg_d < FASTCAP ? deg_d : FASTCAP;
    const int nv8   = (nv + 7) & ~7;

    // ---- Phase A: raw exps -> LDS, denom partials (invalid lanes = zero pad) ----
    float dl0 = 0.f, dl1 = 0.f, dl2 = 0.f, dl3 = 0.f;
    for (int base = 0; base < deg_d; base += 64) {
        int j = base + lane;
        bool valid = j < deg_d;
        int sv = valid ? csr_src[beg + j] : 0;
        float4 as = a_src4[sv];
        float e0 = valid ? __expf(lrelu(as.x + ad.x)) : 0.f;
        float e1 = valid ? __expf(lrelu(as.y + ad.y)) : 0.f;
        float e2 = valid ? __expf(lrelu(as.z + ad.z)) : 0.f;
        float e3 = valid ? __expf(lrelu(as.w + ad.w)) : 0.f;
        dl0 += e0; dl1 += e1; dl2 += e2; dl3 += e3;
        if (j < nv8) sl[j] = make_uint4(pk_f16(e0, e1), pk_f16(e2, e3),
                                        valid ? (unsigned)sv : 0u, 0u);
    }
    __builtin_amdgcn_wave_barrier();

    // self-loop raw exps (wave-uniform)
    float es0 = __expf(lrelu(asd.x + ad.x));
    float es1 = __expf(lrelu(asd.y + ad.y));
    float es2 = __expf(lrelu(asd.z + ad.z));
    float es3 = __expf(lrelu(asd.w + ad.w));

    // ---- Phase B prologue: 8 slot reads + 8 gathers in flight ----
    float a0 = 0.f, a1 = 0.f, a2 = 0.f, a3 = 0.f;
    uint4 c0, c1, c2, c3, c4, c5, c6, c7;
    uint2 h0, h1, h2, h3, h4, h5, h6, h7;
    if (nv8 >= 8) {
        c0 = sl[0]; c1 = sl[1]; c2 = sl[2]; c3 = sl[3];
        c4 = sl[4]; c5 = sl[5]; c6 = sl[6]; c7 = sl[7];
        h0 = hp[(size_t)c0.z * CDIM + lane];
        h1 = hp[(size_t)c1.z * CDIM + lane];
        h2 = hp[(size_t)c2.z * CDIM + lane];
        h3 = hp[(size_t)c3.z * CDIM + lane];
        h4 = hp[(size_t)c4.z * CDIM + lane];
        h5 = hp[(size_t)c5.z * CDIM + lane];
        h6 = hp[(size_t)c6.z * CDIM + lane];
        h7 = hp[(size_t)c7.z * CDIM + lane];
    }

    // ---- denominators: shuffle chains overlap the in-flight gathers ----
    float r0 = __builtin_amdgcn_rcpf(wave_sum(dl0) + es0);
    float r1 = __builtin_amdgcn_rcpf(wave_sum(dl1) + es1);
    float r2 = __builtin_amdgcn_rcpf(wave_sum(dl2) + es2);
    float r3 = __builtin_amdgcn_rcpf(wave_sum(dl3) + es3);

    // ---- Phase B main loop: 8-deep register pipeline ----
    if (nv8 >= 8) {
        int j = 0;
        for (; j + 15 < nv8; j += 8) {
            uint4 n0 = sl[j + 8],  n1 = sl[j + 9],  n2 = sl[j + 10], n3 = sl[j + 11];
            uint4 n4 = sl[j + 12], n5 = sl[j + 13], n6 = sl[j + 14], n7 = sl[j + 15];
            uint2 g0 = hp[(size_t)n0.z * CDIM + lane];
            uint2 g1 = hp[(size_t)n1.z * CDIM + lane];
            uint2 g2 = hp[(size_t)n2.z * CDIM + lane];
            uint2 g3 = hp[(size_t)n3.z * CDIM + lane];
            uint2 g4 = hp[(size_t)n4.z * CDIM + lane];
            uint2 g5 = hp[(size_t)n5.z * CDIM + lane];
            uint2 g6 = hp[(size_t)n6.z * CDIM + lane];
            uint2 g7 = hp[(size_t)n7.z * CDIM + lane];
            acc_edge(c0, h0, a0, a1, a2, a3);
            acc_edge(c1, h1, a0, a1, a2, a3);
            acc_edge(c2, h2, a0, a1, a2, a3);
            acc_edge(c3, h3, a0, a1, a2, a3);
            acc_edge(c4, h4, a0, a1, a2, a3);
            acc_edge(c5, h5, a0, a1, a2, a3);
            acc_edge(c6, h6, a0, a1, a2, a3);
            acc_edge(c7, h7, a0, a1, a2, a3);
            c0 = n0; c1 = n1; c2 = n2; c3 = n3;
            c4 = n4; c5 = n5; c6 = n6; c7 = n7;
            h0 = g0; h1 = g1; h2 = g2; h3 = g3;
            h4 = g4; h5 = g5; h6 = g6; h7 = g7;
        }
        acc_edge(c0, h0, a0, a1, a2, a3);
        acc_edge(c1, h1, a0, a1, a2, a3);
        acc_edge(c2, h2, a0, a1, a2, a3);
        acc_edge(c3, h3, a0, a1, a2, a3);
        acc_edge(c4, h4, a0, a1, a2, a3);
        acc_edge(c5, h5, a0, a1, a2, a3);
        acc_edge(c6, h6, a0, a1, a2, a3);
        acc_edge(c7, h7, a0, a1, a2, a3);
    }

    // ---- slow path: deg > FASTCAP (recompute raw exps) ----
    for (int base = FASTCAP; base < deg_d; base += 64) {
        int jj = base + lane;
        bool valid = jj < deg_d;
        int sv = valid ? csr_src[beg + jj] : 0;
        float4 as = a_src4[sv];
        float e0 = valid ? __expf(lrelu(as.x + ad.x)) : 0.f;
        float e1 = valid ? __expf(lrelu(as.y + ad.y)) : 0.f;
        float e2 = valid ? __expf(lrelu(as.z + ad.z)) : 0.f;
        float e3 = valid ? __expf(lrelu(as.w + ad.w)) : 0.f;
        sl[lane] = make_uint4(pk_f16(e0, e1), pk_f16(e2, e3),
                              valid ? (unsigned)sv : 0u, 0u);
        __builtin_amdgcn_wave_barrier();
        int nav = deg_d - base; if (nav > 64) nav = 64;
        for (int q = 0; q < nav; ++q) {
            uint4 t0 = sl[q];
            uint2 hq = hp[(size_t)t0.z * CDIM + lane];
            acc_edge(t0, hq, a0, a1, a2, a3);
        }
        __builtin_amdgcn_wave_barrier();
    }

    // ---- epilogue: self-loop + normalize + mean + bias + LN + PReLU ----
    half2_t hd01 = as_h2(hd.x), hd23 = as_h2(hd.y);
    a0 = fmaf(es0, (float)hd01.x, a0);
    a1 = fmaf(es1, (float)hd01.y, a1);
    a2 = fmaf(es2, (float)hd23.x, a2);
    a3 = fmaf(es3, (float)hd23.y, a3);

    float v = 0.25f * (a0 * r0 + a1 * r1 + a2 * r2 + a3 * r3) + bl;
    float mu  = wave_sum(v) * (1.f / 64.f);
    float df  = v - mu;
    float var = wave_sum(df * df) * (1.f / 64.f);
    float rs  = rsqrtf(var + 1e-5f);
    float o   = df * rs * gl + bt;
    o = o >= 0.f ? o : pw * o;
    out[(size_t)d * CDIM + lane] = o;
}

extern "C" void kernel_launch(void* const* d_in, const int* in_sizes, int n_in,
                              void* d_out, int out_size, void* d_ws, size_t ws_size,
                              hipStream_t stream)
{
    const float* x       = (const float*)d_in[0];
    const int*   ei      = (const int*)  d_in[1];
    const float* W       = (const float*)d_in[2];
    const float* att_src = (const float*)d_in[3];
    const float* att_dst = (const float*)d_in[4];
    const float* bias    = (const float*)d_in[5];
    const float* gamma   = (const float*)d_in[6];
    const float* beta    = (const float*)d_in[7];
    const float* prelu   = (const float*)d_in[8];

    const int N = in_sizes[0] / INDIM;
    const int E = in_sizes[1] / 2;
    float* out = (float*)d_out;

    const int NBUK = (N + 255) >> 8;            // buckets of 256 nodes
    const int EPB  = (E + NPB - 1) / NPB;       // edges per partition block
    const int NCNT = NBUK * NPB;                // counts length

    // workspace layout
    uint2*    hp     = (uint2*)d_ws;                      // N*64 uint2 (25.6 MB)
    float*    a_src  = (float*)(hp + (size_t)N * CDIM);   // N*4 f
    float*    a_dst  = a_src + (size_t)N * HEADS;         // N*4 f
    int*      deg    = (int*)(a_dst + (size_t)N * HEADS); // N
    int*      off    = deg + N;                           // N
    int*      counts = off + N;                           // NBUK*256
    int*      bsum   = counts + NCNT;                     // <=1024
    unsigned* srt    = (unsigned*)(bsum + 1024);          // E u32 (packed)
    int*      csr    = (int*)(srt + E);                   // E
    unsigned short* Waug = (unsigned short*)(csr + E);    // 272*128 bf16

    k_count_prep<<<NPB, 256, 0, stream>>>(ei, E, EPB, NBUK, counts,
                                          W, att_src, att_dst, Waug);
    k_scan1<<<NBUK, 256, 0, stream>>>(counts, bsum, NCNT);
    k_scanip2<<<NBUK, 256, 0, stream>>>(counts, bsum, NBUK, NCNT);
    k_part<<<NPB, 256, 0, stream>>>(ei, E, EPB, NBUK, counts, srt);
    k_bcsr<<<NBUK, 256, 0, stream>>>(srt, counts, E, N, NBUK, deg, off, csr);

    gemm_mfma<<<(N + 127) / 128, 512, 69632, stream>>>(
        x, Waug, hp, a_src, a_dst, N);

    aggr_fused<<<(N + 3) / 4, 256, 0, stream>>>(
        off, deg, csr, (const float4*)a_src, (const float4*)a_dst, hp,
        bias, gamma, beta, prelu, out, N);
}

// Round 14
// 115.733 us; speedup vs baseline: 1.0028x; 1.0028x over previous
//
#include <hip/hip_runtime.h>

#define HEADS 4
#define CDIM  64
#define INDIM 128
#define NEG   0.2f
#define CAP     256   // LDS edge slots per wave (aggr)
#define FASTCAP 252   // fast-path edge limit
#define NPB     256   // partition blocks for bucket sort

typedef __attribute__((ext_vector_type(8))) short short8;
typedef __attribute__((ext_vector_type(4))) float f32x4;
typedef _Float16 half2_t __attribute__((ext_vector_type(2)));

__device__ __forceinline__ float wave_sum(float v) {
#pragma unroll
    for (int o = 32; o > 0; o >>= 1) v += __shfl_xor(v, o, 64);
    return v;
}
__device__ __forceinline__ int wave_sum_i(int v) {
#pragma unroll
    for (int o = 32; o > 0; o >>= 1) v += __shfl_xor(v, o, 64);
    return v;
}

// f32 -> bf16 bits (RNE) — for the MFMA operand prep only
__device__ __forceinline__ unsigned short f2bf(float f) {
    unsigned u = __float_as_uint(f);
    u = (u + 0x7FFFu + ((u >> 16) & 1u)) >> 16;
    return (unsigned short)u;
}

__device__ __forceinline__ unsigned pk_f16(float a, float b) {
    auto h = __builtin_amdgcn_cvt_pkrtz(a, b);   // __fp16 x2
    return __builtin_bit_cast(unsigned, h);
}
__device__ __forceinline__ half2_t as_h2(unsigned u) {
    return __builtin_bit_cast(half2_t, u);
}

#if __has_builtin(__builtin_amdgcn_fdot2)
__device__ __forceinline__ float fdot2(unsigned a, unsigned b, float c) {
    return __builtin_amdgcn_fdot2(as_h2(a), as_h2(b), c, false);
}
#else
__device__ __forceinline__ float fdot2(unsigned a, unsigned b, float c) {
    half2_t ha = as_h2(a), hb = as_h2(b);
    return c + (float)ha.x * (float)hb.x + (float)ha.y * (float)hb.y;
}
#endif

__device__ __forceinline__ float lrelu(float a) { return a >= 0.f ? a : NEG * a; }

// ---------------- count (bucket hist) + Waug prep, merged ----------------
__global__ __launch_bounds__(256) void k_count_prep(const int* __restrict__ ei,
    int E, int EPB, int NBUK, int* __restrict__ counts,
    const float* __restrict__ W, const float* __restrict__ att_src,
    const float* __restrict__ att_dst, unsigned short* __restrict__ Waug)
{
    __shared__ int hist[256];
    const int t = threadIdx.x, blk = blockIdx.x;
    hist[t] = 0;
    __syncthreads();
    const int e0 = blk * EPB;
    for (int j = t; j < EPB; j += 256) {
        int e = e0 + j;
        if (e < E) atomicAdd(&hist[ei[E + e] >> 8], 1);   // LDS atomic
    }
    __syncthreads();
    if (t < NBUK) counts[t * NPB + blk] = hist[t];

    // Waug prep: one (col,k) entry per global thread
    int idx = blk * 256 + t;
    if (idx < 272 * 128) {
        int c = idx >> 7, k = idx & 127;
        float val;
        if (c < 256) {
            val = W[k * 256 + c];
        } else if (c < 260) {
            int q = c - 256; float s = 0.f;
            for (int j = 0; j < 64; ++j) s += W[k * 256 + q * 64 + j] * att_src[q * 64 + j];
            val = s;
        } else if (c < 264) {
            int q = c - 260; float s = 0.f;
            for (int j = 0; j < 64; ++j) s += W[k * 256 + q * 64 + j] * att_dst[q * 64 + j];
            val = s;
        } else {
            val = 0.f;
        }
        Waug[c * 128 + k] = f2bf(val);
    }
}

// ---------------- scan, phase 1: per-block sums ----------------
__global__ __launch_bounds__(256) void k_scan1(const int* __restrict__ arr,
    int* __restrict__ bsum, int n)
{
    const int t = threadIdx.x, lane = t & 63, wv = t >> 6;
    int gid = blockIdx.x * 256 + t;
    int v = (gid < n) ? arr[gid] : 0;
    v = wave_sum_i(v);
    __shared__ int ws[4];
    if (lane == 0) ws[wv] = v;
    __syncthreads();
    if (t == 0) bsum[blockIdx.x] = ws[0] + ws[1] + ws[2] + ws[3];
}

// ---------------- scan, phase 2: finalize in place (self-computed prefix) ----------------
__global__ __launch_bounds__(256) void k_scanip2(int* __restrict__ arr,
    const int* __restrict__ bsum, int NB, int n)
{
    __shared__ int wred[4];
    __shared__ int wtot[4];
    __shared__ int spre;
    const int t = threadIdx.x, lane = t & 63, wv = t >> 6, b = blockIdx.x;

    int u0 = (t < NB && t < b) ? bsum[t] : 0;
    u0 = wave_sum_i(u0);
    if (lane == 0) wred[wv] = u0;
    __syncthreads();
    if (t == 0) spre = wred[0] + wred[1] + wred[2] + wred[3];
    __syncthreads();

    int gid = b * 256 + t;
    int v = (gid < n) ? arr[gid] : 0;
    int inc = v;
#pragma unroll
    for (int o = 1; o < 64; o <<= 1) {
        int u = __shfl_up(inc, o, 64);
        if (lane >= o) inc += u;
    }
    if (lane == 63) wtot[wv] = inc;
    __syncthreads();
    int wpre = 0;
    for (int w = 0; w < wv; ++w) wpre += wtot[w];
    int ex = inc - v + wpre + spre;
    if (gid < n) arr[gid] = ex;
}

// ---------------- partition: packed u32 (src<<8 | dst&255) ----------------
__global__ __launch_bounds__(256) void k_part(const int* __restrict__ ei,
    int E, int EPB, int NBUK, const int* __restrict__ counts,
    unsigned* __restrict__ srt)
{
    __shared__ int cb[256];
    const int t = threadIdx.x, blk = blockIdx.x;
    if (t < NBUK) cb[t] = counts[t * NPB + blk];
    __syncthreads();
    const int e0 = blk * EPB;
    for (int j = t; j < EPB; j += 256) {
        int e = e0 + j;
        if (e < E) {
            int s = ei[e], d = ei[E + e];
            int pos = atomicAdd(&cb[d >> 8], 1);   // LDS atomic
            srt[pos] = ((unsigned)s << 8) | ((unsigned)d & 255u);
        }
    }
}

// ---------------- per-bucket CSR ----------------
__global__ __launch_bounds__(256) void k_bcsr(const unsigned* __restrict__ srt,
    const int* __restrict__ counts, int E, int N, int NBUK,
    int* __restrict__ deg, int* __restrict__ off, int* __restrict__ csr)
{
    __shared__ int h[256];
    __shared__ int cur[256];
    __shared__ int wt[4];
    const int t = threadIdx.x, b = blockIdx.x;
    const int bb0 = counts[b * NPB];
    const int bb1 = (b + 1 < NBUK) ? counts[(b + 1) * NPB] : E;
    const int ne = bb1 - bb0;

    h[t] = 0;
    __syncthreads();
    for (int j = t; j < ne; j += 256) atomicAdd(&h[srt[bb0 + j] & 255u], 1);
    __syncthreads();

    int v = h[t];
    const int lane = t & 63, wv = t >> 6;
    int inc = v;
#pragma unroll
    for (int o = 1; o < 64; o <<= 1) {
        int u = __shfl_up(inc, o, 64);
        if (lane >= o) inc += u;
    }
    if (lane == 63) wt[wv] = inc;
    __syncthreads();
    int wpre = 0;
    for (int w = 0; w < wv; ++w) wpre += wt[w];
    int ex = inc - v + wpre;

    int node = (b << 8) + t;
    if (node < N) { deg[node] = v; off[node] = bb0 + ex; }
    cur[t] = bb0 + ex;
    __syncthreads();

    for (int j = t; j < ne; j += 256) {
        unsigned u = srt[bb0 + j];
        int pos = atomicAdd(&cur[u & 255u], 1);   // LDS atomic
        csr[pos] = (int)(u >> 8);
    }
}

// ---------------- MFMA projection: h (f16-packed) + logits ----------------
__global__ __launch_bounds__(512) void gemm_mfma(
    const float* __restrict__ x, const unsigned short* __restrict__ Waug,
    uint2* __restrict__ hp, float* __restrict__ a_src, float* __restrict__ a_dst,
    int N)
{
    extern __shared__ char smem[];
    const int t = threadIdx.x;

    const uint4* srcw = (const uint4*)Waug;
    for (int i = t; i < 272 * 16; i += 512) {
        int col = i >> 4, kc = i & 15;
        int off = col * 256 + ((kc * 16) ^ ((col & 7) << 4));
        *(uint4*)(smem + off) = srcw[i];
    }
    __syncthreads();

    const int lane = t & 63, wv = t >> 6;
    const int l = lane & 15, g = lane >> 4;
    const int rowbase = blockIdx.x * 128 + wv * 16;

    int anode = rowbase + l; if (anode >= N) anode = N - 1;
    const float4* xrow = (const float4*)(x + (size_t)anode * INDIM);

    short8 af[4];
#pragma unroll
    for (int ks = 0; ks < 4; ++ks) {
        float4 x0 = xrow[ks * 8 + g * 2];
        float4 x1 = xrow[ks * 8 + g * 2 + 1];
        short8 a;
        a[0] = (short)f2bf(x0.x); a[1] = (short)f2bf(x0.y);
        a[2] = (short)f2bf(x0.z); a[3] = (short)f2bf(x0.w);
        a[4] = (short)f2bf(x1.x); a[5] = (short)f2bf(x1.y);
        a[6] = (short)f2bf(x1.z); a[7] = (short)f2bf(x1.w);
        af[ks] = a;
    }

    f32x4 acc[17];
    const f32x4 zero = {0.f, 0.f, 0.f, 0.f};
#pragma unroll
    for (int tt = 0; tt < 17; ++tt) acc[tt] = zero;

    const int base_b = l * 256;
#pragma unroll
    for (int ks = 0; ks < 4; ++ks) {
        const int koff = (ks * 64 + g * 16) ^ ((l & 7) << 4);
#pragma unroll
        for (int tt = 0; tt < 17; ++tt) {
            short8 bf = *(const short8*)(smem + tt * 4096 + base_b + koff);
            acc[tt] = __builtin_amdgcn_mfma_f32_16x16x32_bf16(af[ks], bf, acc[tt], 0, 0, 0);
        }
    }

#pragma unroll
    for (int j = 0; j < 4; ++j) {
        int node = rowbase + g * 4 + j;
        if (node < N) {
#pragma unroll
            for (int u = 0; u < 4; ++u) {
                int ch = l + 16 * u;
                hp[(size_t)node * CDIM + ch] = make_uint2(
                    pk_f16(acc[u][j],     acc[4 + u][j]),
                    pk_f16(acc[8 + u][j], acc[12 + u][j]));
            }
            if (l < 4)      a_src[node * 4 + l]       = acc[16][j];
            else if (l < 8) a_dst[node * 4 + (l - 4)] = acc[16][j];
        }
    }
}

// ---------------- fused aggregation + LayerNorm + PReLU ----------------
// R11-proven structure: Phase A owner-lane raw exps -> LDS + denom partials;
// rescale pass folds 1/den into f16 weights; Phase B = 1 uniform ds_read_b128
// + 1 hp gather + 2 fdot2 per edge, 4-deep register double-buffer.
// VGPR ~32 -> ~73% occupancy; TLP > per-wave ILP for this gather pattern.
__global__ __launch_bounds__(256) void aggr_fused(
    const int* __restrict__ off, const int* __restrict__ deg,
    const int* __restrict__ csr_src,
    const float4* __restrict__ a_src4, const float4* __restrict__ a_dst4,
    const uint2* __restrict__ hp,
    const float* __restrict__ bias, const float* __restrict__ gamma,
    const float* __restrict__ beta, const float* __restrict__ prelu,
    float* __restrict__ out, int N)
{
    __shared__ uint4 slot[4][CAP];
    const int wv   = threadIdx.x >> 6;
    const int lane = threadIdx.x & 63;
    const int wid  = (int)(blockIdx.x * 4u + wv);
    if (wid >= N) return;
    const int d = wid;
    uint4* sl = slot[wv];

    const float bl = bias[lane], gl = gamma[lane], bt = beta[lane], pw = prelu[0];
    const float4 ad = a_dst4[d];   // wave-uniform
    const int deg_d = deg[d];
    const int beg   = off[d];
    const int nv    = deg_d < FASTCAP ? deg_d : FASTCAP;
    const int nv4   = (nv + 3) & ~3;

    // ---- Phase A: raw exps -> LDS, denom partials ----
    float dl0 = 0.f, dl1 = 0.f, dl2 = 0.f, dl3 = 0.f;
    for (int base = 0; base < deg_d; base += 64) {
        int j = base + lane;
        bool valid = j < deg_d;
        int sv = valid ? csr_src[beg + j] : 0;
        float4 as = a_src4[sv];
        float e0 = valid ? __expf(lrelu(as.x + ad.x)) : 0.f;
        float e1 = valid ? __expf(lrelu(as.y + ad.y)) : 0.f;
        float e2 = valid ? __expf(lrelu(as.z + ad.z)) : 0.f;
        float e3 = valid ? __expf(lrelu(as.w + ad.w)) : 0.f;
        dl0 += e0; dl1 += e1; dl2 += e2; dl3 += e3;
        if (j < CAP) sl[j] = make_uint4(pk_f16(e0, e1), pk_f16(e2, e3), (unsigned)sv, 0u);
    }

    // self-loop exps (wave-uniform)
    float4 asd = a_src4[d];
    float es0 = __expf(lrelu(asd.x + ad.x));
    float es1 = __expf(lrelu(asd.y + ad.y));
    float es2 = __expf(lrelu(asd.z + ad.z));
    float es3 = __expf(lrelu(asd.w + ad.w));

    float r0 = __builtin_amdgcn_rcpf(wave_sum(dl0) + es0);
    float r1 = __builtin_amdgcn_rcpf(wave_sum(dl1) + es1);
    float r2 = __builtin_amdgcn_rcpf(wave_sum(dl2) + es2);
    float r3 = __builtin_amdgcn_rcpf(wave_sum(dl3) + es3);

    // ---- rescale pass: w = e * r (owner lane); pad [nv, nv4) with zeros ----
    for (int base = 0; base < nv4; base += 64) {
        int j = base + lane;
        if (j < nv) {
            uint2 ev = *(const uint2*)&sl[j];
            half2_t e01 = as_h2(ev.x), e23 = as_h2(ev.y);
            *(uint2*)&sl[j] = make_uint2(
                pk_f16((float)e01.x * r0, (float)e01.y * r1),
                pk_f16((float)e23.x * r2, (float)e23.y * r3));
        } else if (j < nv4) {
            sl[j] = make_uint4(0u, 0u, 0u, 0u);   // zero weight, sv=0 -> no-op
        }
    }
    __builtin_amdgcn_wave_barrier();

    // ---- Phase B: accumulate (self-loop init) ----
    uint2 hd = hp[(size_t)d * CDIM + lane];
    unsigned pw01 = pk_f16(es0 * r0, es1 * r1);
    unsigned pw23 = pk_f16(es2 * r2, es3 * r3);
    float acc01 = fdot2(pw01, hd.x, 0.f);
    float acc23 = fdot2(pw23, hd.y, 0.f);

    if (nv4 >= 8) {
        uint4 c0 = sl[0], c1 = sl[1], c2 = sl[2], c3 = sl[3];
        uint2 h0 = hp[(size_t)c0.z * CDIM + lane];
        uint2 h1 = hp[(size_t)c1.z * CDIM + lane];
        uint2 h2 = hp[(size_t)c2.z * CDIM + lane];
        uint2 h3 = hp[(size_t)c3.z * CDIM + lane];
        int j = 0;
        for (; j + 7 < nv4; j += 4) {
            uint4 n0 = sl[j + 4], n1 = sl[j + 5], n2 = sl[j + 6], n3 = sl[j + 7];
            uint2 g0 = hp[(size_t)n0.z * CDIM + lane];
            uint2 g1 = hp[(size_t)n1.z * CDIM + lane];
            uint2 g2 = hp[(size_t)n2.z * CDIM + lane];
            uint2 g3 = hp[(size_t)n3.z * CDIM + lane];
            acc01 = fdot2(c0.x, h0.x, acc01); acc23 = fdot2(c0.y, h0.y, acc23);
            acc01 = fdot2(c1.x, h1.x, acc01); acc23 = fdot2(c1.y, h1.y, acc23);
            acc01 = fdot2(c2.x, h2.x, acc01); acc23 = fdot2(c2.y, h2.y, acc23);
            acc01 = fdot2(c3.x, h3.x, acc01); acc23 = fdot2(c3.y, h3.y, acc23);
            c0 = n0; c1 = n1; c2 = n2; c3 = n3;
            h0 = g0; h1 = g1; h2 = g2; h3 = g3;
        }
        acc01 = fdot2(c0.x, h0.x, acc01); acc23 = fdot2(c0.y, h0.y, acc23);
        acc01 = fdot2(c1.x, h1.x, acc01); acc23 = fdot2(c1.y, h1.y, acc23);
        acc01 = fdot2(c2.x, h2.x, acc01); acc23 = fdot2(c2.y, h2.y, acc23);
        acc01 = fdot2(c3.x, h3.x, acc01); acc23 = fdot2(c3.y, h3.y, acc23);
    } else if (nv4 == 4) {
        uint4 c0 = sl[0], c1 = sl[1], c2 = sl[2], c3 = sl[3];
        uint2 h0 = hp[(size_t)c0.z * CDIM + lane];
        uint2 h1 = hp[(size_t)c1.z * CDIM + lane];
        uint2 h2 = hp[(size_t)c2.z * CDIM + lane];
        uint2 h3 = hp[(size_t)c3.z * CDIM + lane];
        acc01 = fdot2(c0.x, h0.x, acc01); acc23 = fdot2(c0.y, h0.y, acc23);
        acc01 = fdot2(c1.x, h1.x, acc01); acc23 = fdot2(c1.y, h1.y, acc23);
        acc01 = fdot2(c2.x, h2.x, acc01); acc23 = fdot2(c2.y, h2.y, acc23);
        acc01 = fdot2(c3.x, h3.x, acc01); acc23 = fdot2(c3.y, h3.y, acc23);
    }

    // ---- slow path: deg > FASTCAP (recompute with known r) ----
    for (int base = FASTCAP; base < deg_d; base += 64) {
        int jj = base + lane;
        bool valid = jj < deg_d;
        int sv = valid ? csr_src[beg + jj] : 0;
        float4 as = a_src4[sv];
        float e0 = valid ? __expf(lrelu(as.x + ad.x)) : 0.f;
        float e1 = valid ? __expf(lrelu(as.y + ad.y)) : 0.f;
        float e2 = valid ? __expf(lrelu(as.z + ad.z)) : 0.f;
        float e3 = valid ? __expf(lrelu(as.w + ad.w)) : 0.f;
        sl[lane] = make_uint4(pk_f16(e0 * r0, e1 * r1), pk_f16(e2 * r2, e3 * r3),
                              (unsigned)sv, 0u);
        __builtin_amdgcn_wave_barrier();
        int nav = deg_d - base; if (nav > 64) nav = 64;
        for (int q = 0; q < nav; ++q) {
            uint4 t0 = sl[q];
            uint2 h0 = hp[(size_t)t0.z * CDIM + lane];
            acc01 = fdot2(t0.x, h0.x, acc01);
            acc23 = fdot2(t0.y, h0.y, acc23);
        }
        __builtin_amdgcn_wave_barrier();
    }

    // ---- epilogue: mean over heads + bias + LN + PReLU ----
    float v = 0.25f * (acc01 + acc23) + bl;
    float mu  = wave_sum(v) * (1.f / 64.f);
    float df  = v - mu;
    float var = wave_sum(df * df) * (1.f / 64.f);
    float rs  = rsqrtf(var + 1e-5f);
    float o   = df * rs * gl + bt;
    o = o >= 0.f ? o : pw * o;
    out[(size_t)d * CDIM + lane] = o;
}

extern "C" void kernel_launch(void* const* d_in, const int* in_sizes, int n_in,
                              void* d_out, int out_size, void* d_ws, size_t ws_size,
                              hipStream_t stream)
{
    const float* x       = (const float*)d_in[0];
    const int*   ei      = (const int*)  d_in[1];
    const float* W       = (const float*)d_in[2];
    const float* att_src = (const float*)d_in[3];
    const float* att_dst = (const float*)d_in[4];
    const float* bias    = (const float*)d_in[5];
    const float* gamma   = (const float*)d_in[6];
    const float* beta    = (const float*)d_in[7];
    const float* prelu   = (const float*)d_in[8];

    const int N = in_sizes[0] / INDIM;
    const int E = in_sizes[1] / 2;
    float* out = (float*)d_out;

    const int NBUK = (N + 255) >> 8;            // buckets of 256 nodes
    const int EPB  = (E + NPB - 1) / NPB;       // edges per partition block
    const int NCNT = NBUK * NPB;                // counts length

    // workspace layout
    uint2*    hp     = (uint2*)d_ws;                      // N*64 uint2 (25.6 MB)
    float*    a_src  = (float*)(hp + (size_t)N * CDIM);   // N*4 f
    float*    a_dst  = a_src + (size_t)N * HEADS;         // N*4 f
    int*      deg    = (int*)(a_dst + (size_t)N * HEADS); // N
    int*      off    = deg + N;                           // N
    int*      counts = off + N;                           // NBUK*256
    int*      bsum   = counts + NCNT;                     // <=1024
    unsigned* srt    = (unsigned*)(bsum + 1024);          // E u32 (packed)
    int*      csr    = (int*)(srt + E);                   // E
    unsigned short* Waug = (unsigned short*)(csr + E);    // 272*128 bf16

    k_count_prep<<<NPB, 256, 0, stream>>>(ei, E, EPB, NBUK, counts,
                                          W, att_src, att_dst, Waug);
    k_scan1<<<NBUK, 256, 0, stream>>>(counts, bsum, NCNT);
    k_scanip2<<<NBUK, 256, 0, stream>>>(counts, bsum, NBUK, NCNT);
    k_part<<<NPB, 256, 0, stream>>>(ei, E, EPB, NBUK, counts, srt);
    k_bcsr<<<NBUK, 256, 0, stream>>>(srt, counts, E, N, NBUK, deg, off, csr);

    gemm_mfma<<<(N + 127) / 128, 512, 69632, stream>>>(
        x, Waug, hp, a_src, a_dst, N);

    aggr_fused<<<(N + 3) / 4, 256, 0, stream>>>(
        off, deg, csr, (const float4*)a_src, (const float4*)a_dst, hp,
        bias, gamma, beta, prelu, out, N);
}